// Round 4
// baseline (852.977 us; speedup 1.0000x reference)
//
#include <hip/hip_runtime.h>
#include <stdint.h>

#define LN2   0.6931471805599453f
#define LOG2E 1.4426950408889634f

static constexpr int B = 64, T = 2000, C = 512, L = 200;
static constexpr int CH = 10;          // DP steps per prefetch chunk
static constexpr int NC = T / CH;      // 200 chunks (exact)

// round-to-nearest-even f32 -> bf16
static __device__ __forceinline__ uint16_t f2bf(float f) {
    uint32_t u = __float_as_uint(f);
    return (uint16_t)((u + 0x7FFFu + ((u >> 16) & 1u)) >> 16);
}

// Kernel A: per (b,t) row, softmax probs at the 200 target ids (LINEAR bf16).
// One wave per row, 4 waves per block; LDS is wave-private (no barrier).
__global__ __launch_bounds__(256) void emit_kernel(
    const float* __restrict__ x, const int* __restrict__ tgt,
    uint16_t* __restrict__ emit)
{
    const int wid  = threadIdx.x >> 6;
    const int lane = threadIdx.x & 63;
    const int row  = blockIdx.x * 4 + wid;      // in [0, B*T), grid exact
    const int b    = row / T;
    const float* xr = x + (size_t)row * C;

    __shared__ float lds[4][C];
    float* e = lds[wid];

    const float4 v0 = *(const float4*)(xr + lane * 4);
    const float4 v1 = *(const float4*)(xr + C / 2 + lane * 4);

    float m = fmaxf(fmaxf(fmaxf(v0.x, v0.y), fmaxf(v0.z, v0.w)),
                    fmaxf(fmaxf(v1.x, v1.y), fmaxf(v1.z, v1.w)));
    #pragma unroll
    for (int off = 32; off; off >>= 1) m = fmaxf(m, __shfl_xor(m, off));

    float4 E0, E1;
    E0.x = exp2f((v0.x - m) * LOG2E); E0.y = exp2f((v0.y - m) * LOG2E);
    E0.z = exp2f((v0.z - m) * LOG2E); E0.w = exp2f((v0.w - m) * LOG2E);
    E1.x = exp2f((v1.x - m) * LOG2E); E1.y = exp2f((v1.y - m) * LOG2E);
    E1.z = exp2f((v1.z - m) * LOG2E); E1.w = exp2f((v1.w - m) * LOG2E);

    *(float4*)&e[lane * 4]         = E0;
    *(float4*)&e[C / 2 + lane * 4] = E1;

    float s = (E0.x + E0.y + E0.z + E0.w) + (E1.x + E1.y + E1.z + E1.w);
    #pragma unroll
    for (int off = 32; off; off >>= 1) s += __shfl_xor(s, off);

    if (lane < L / 4) {  // 50 lanes, 4 targets each
        const int4 tv = *(const int4*)(tgt + b * L + lane * 4);
        const float invs = 1.0f / s;
        float p0 = e[tv.x] * invs;
        float p1 = e[tv.y] * invs;
        float p2 = e[tv.z] * invs;
        float p3 = e[tv.w] * invs;
        uint2 w;
        w.x = (uint32_t)f2bf(p0) | ((uint32_t)f2bf(p1) << 16);
        w.y = (uint32_t)f2bf(p2) | ((uint32_t)f2bf(p3) << 16);
        *(uint2*)(emit + (size_t)row * L + lane * 4) = w;
    }
}

// Kernel B: LINEAR-domain DP with per-lane power-of-2 scaling.
// One wave per batch; lane holds l = 4*lane..4*lane+3 (lanes 0..49 active).
//   A[l] <- p[t,l] * (A[l] + A[l-1]), all >= 0.
// Per-lane int exponent e (log2 scale); rescale to lane-local max every 5
// steps; cross-lane carry multiplied by exact 2^(e_prev - e_cur) (split into
// two factors f1*f2 so |d| <= 252 is exact). Zero lanes adopt upstream e so
// the propagation frontier never underflows.
__global__ __launch_bounds__(64, 1) __attribute__((amdgpu_waves_per_eu(1, 1)))
void dp_kernel(const uint16_t* __restrict__ emit, float* __restrict__ partial)
{
    const int b    = blockIdx.x;
    const int lane = threadIdx.x;
    const int l0   = lane * 4;
    const bool act = (l0 < L);
    const uint16_t* rowp = emit + (size_t)b * T * L + l0;

    float A0 = 0.f, A1 = 0.f, A2 = 0.f, A3 = 0.f;
    int   e  = 0;                 // per-lane log2 scale: true alpha = A * 2^e
    float f1 = 1.f, f2 = 1.f;     // carry factor 2^(e_prev - e_cur) = f1*f2
    bool first = true;

    uint2 bufA[CH], bufB[CH], bufC[CH], bufD[CH];

#define LOADC(BUF, CBASE) do {                                               \
    const uint16_t* _p = rowp + (size_t)(CBASE) * (CH * L);                  \
    _Pragma("unroll")                                                        \
    for (int _j = 0; _j < CH; ++_j)                                          \
        BUF[_j] = act ? *(const uint2*)(_p + _j * L) : make_uint2(0u, 0u);   \
    __builtin_amdgcn_sched_barrier(0); /* pin load issue here */             \
} while (0)

#define RESCALE() do {                                                       \
    uint32_t _b0 = __float_as_uint(A0), _b1 = __float_as_uint(A1);           \
    uint32_t _b2 = __float_as_uint(A2), _b3 = __float_as_uint(A3);           \
    uint32_t _m = max(max(_b0, _b1), max(_b2, _b3)); /* all >= 0 */          \
    uint32_t _me = _m & 0x7f800000u;                                         \
    bool _nz = (_m != 0u);                                                   \
    float _sc = _nz ? __uint_as_float(0x7F000000u - _me) : 1.0f;             \
    int _de = _nz ? (int)(_me >> 23) - 127 : 0;                              \
    int _epo = __shfl_up(e, 1);                                              \
    e = _nz ? (e + _de) : _epo;          /* zero lanes adopt upstream e */   \
    A0 *= _sc; A1 *= _sc; A2 *= _sc; A3 *= _sc;                              \
    int _ep = __shfl_up(e, 1);                                               \
    int _d = _ep - e;                                                        \
    _d = (_d < -252) ? -252 : ((_d > 252) ? 252 : _d);                       \
    int _d1 = _d >> 1, _d2 = _d - _d1;                                       \
    f1 = __uint_as_float((uint32_t)(127 + _d1) << 23);                       \
    f2 = __uint_as_float((uint32_t)(127 + _d2) << 23);                       \
} while (0)

#define PROC(BUF) do {                                                       \
    _Pragma("unroll")                                                        \
    for (int _j = 0; _j < CH; ++_j) {                                        \
        uint2 _v = BUF[_j];                                                  \
        float _p0 = __uint_as_float(_v.x << 16);                             \
        float _p1 = __uint_as_float(_v.x & 0xffff0000u);                     \
        float _p2 = __uint_as_float(_v.y << 16);                             \
        float _p3 = __uint_as_float(_v.y & 0xffff0000u);                     \
        float _up = __shfl_up(A3, 1);                                        \
        float _cm = _up * f1 * f2;                                           \
        float _fix = (_j == 0 && first) ? 1.0f : 0.0f;                       \
        float _c = (lane == 0) ? _fix : _cm;                                 \
        float _n0 = _p0 * (A0 + _c);                                         \
        float _n1 = _p1 * (A1 + A0);                                         \
        float _n2 = _p2 * (A2 + A1);                                         \
        float _n3 = _p3 * (A3 + A2);                                         \
        A0 = _n0; A1 = _n1; A2 = _n2; A3 = _n3;                              \
        if (_j == 4 || _j == 9) RESCALE();                                   \
    }                                                                        \
    first = false;                                                           \
} while (0)

    LOADC(bufA, 0);
    LOADC(bufB, 1);
    for (int c = 0; c < NC; c += 4) {
        LOADC(bufC, c + 2);
        LOADC(bufD, c + 3);
        PROC(bufA);
        PROC(bufB);
        if (c + 4 < NC) { LOADC(bufA, c + 4); LOADC(bufB, c + 5); }
        PROC(bufC);
        PROC(bufD);
    }

#undef LOADC
#undef RESCALE
#undef PROC

    // true log2 alpha[T-1, L-1] = log2(A3) + e, at lane 49 (l = 199)
    if (lane == 49) {
        partial[b] = (log2f(A3) + (float)e) * LN2;
    }
}

// Kernel C: loss = -mean_b log alpha_b
__global__ __launch_bounds__(64) void reduce_kernel(
    const float* __restrict__ partial, float* __restrict__ out)
{
    const int lane = threadIdx.x;
    float v = (lane < B) ? partial[lane] : 0.f;
    #pragma unroll
    for (int off = 32; off; off >>= 1) v += __shfl_xor(v, off);
    if (lane == 0) out[0] = -v * (1.0f / (float)B);
}

extern "C" void kernel_launch(void* const* d_in, const int* in_sizes, int n_in,
                              void* d_out, int out_size, void* d_ws, size_t ws_size,
                              hipStream_t stream) {
    const float* x   = (const float*)d_in[0];   // [B,T,C] fp32
    const int*   tgt = (const int*)d_in[1];     // [B,L] int32
    uint16_t* emit   = (uint16_t*)d_ws;         // [B,T,L] bf16 linear probs (51.2 MB)
    float* partial   = (float*)((char*)d_ws + (size_t)B * T * L * sizeof(uint16_t));
    float* out       = (float*)d_out;

    emit_kernel<<<B * T / 4, 256, 0, stream>>>(x, tgt, emit);
    dp_kernel<<<B, 64, 0, stream>>>(emit, partial);
    reduce_kernel<<<1, 64, 0, stream>>>(partial, out);
}

// Round 5
// 498.679 us; speedup vs baseline: 1.7105x; 1.7105x over previous
//
#include <hip/hip_runtime.h>
#include <stdint.h>

#define LN2   0.6931471805599453f
#define LOG2E 1.4426950408889634f

static constexpr int B = 64, T = 2000, C = 512, L = 200;
static constexpr int CH   = 16;            // DP steps per chunk
static constexpr int NCH  = T / CH;        // 125 chunks (exact)
static constexpr int CHB  = CH * L * 2;    // 6400 bytes per chunk
static constexpr int NBUF = 8;             // LDS ring slots (51.2 KB)

// round-to-nearest-even f32 -> bf16
static __device__ __forceinline__ uint16_t f2bf(float f) {
    uint32_t u = __float_as_uint(f);
    return (uint16_t)((u + 0x7FFFu + ((u >> 16) & 1u)) >> 16);
}

// Kernel A: per (b,t) row, softmax probs at the 200 target ids (LINEAR bf16).
// One wave per row, 4 waves per block; LDS is wave-private (no barrier).
// UNCHANGED from round 4 (passed, absmax 0.0).
__global__ __launch_bounds__(256) void emit_kernel(
    const float* __restrict__ x, const int* __restrict__ tgt,
    uint16_t* __restrict__ emit)
{
    const int wid  = threadIdx.x >> 6;
    const int lane = threadIdx.x & 63;
    const int row  = blockIdx.x * 4 + wid;      // in [0, B*T), grid exact
    const int b    = row / T;
    const float* xr = x + (size_t)row * C;

    __shared__ float lds[4][C];
    float* e = lds[wid];

    const float4 v0 = *(const float4*)(xr + lane * 4);
    const float4 v1 = *(const float4*)(xr + C / 2 + lane * 4);

    float m = fmaxf(fmaxf(fmaxf(v0.x, v0.y), fmaxf(v0.z, v0.w)),
                    fmaxf(fmaxf(v1.x, v1.y), fmaxf(v1.z, v1.w)));
    #pragma unroll
    for (int off = 32; off; off >>= 1) m = fmaxf(m, __shfl_xor(m, off));

    float4 E0, E1;
    E0.x = exp2f((v0.x - m) * LOG2E); E0.y = exp2f((v0.y - m) * LOG2E);
    E0.z = exp2f((v0.z - m) * LOG2E); E0.w = exp2f((v0.w - m) * LOG2E);
    E1.x = exp2f((v1.x - m) * LOG2E); E1.y = exp2f((v1.y - m) * LOG2E);
    E1.z = exp2f((v1.z - m) * LOG2E); E1.w = exp2f((v1.w - m) * LOG2E);

    *(float4*)&e[lane * 4]         = E0;
    *(float4*)&e[C / 2 + lane * 4] = E1;

    float s = (E0.x + E0.y + E0.z + E0.w) + (E1.x + E1.y + E1.z + E1.w);
    #pragma unroll
    for (int off = 32; off; off >>= 1) s += __shfl_xor(s, off);

    if (lane < L / 4) {  // 50 lanes, 4 targets each
        const int4 tv = *(const int4*)(tgt + b * L + lane * 4);
        const float invs = 1.0f / s;
        float p0 = e[tv.x] * invs;
        float p1 = e[tv.y] * invs;
        float p2 = e[tv.z] * invs;
        float p3 = e[tv.w] * invs;
        uint2 w;
        w.x = (uint32_t)f2bf(p0) | ((uint32_t)f2bf(p1) << 16);
        w.y = (uint32_t)f2bf(p2) | ((uint32_t)f2bf(p3) << 16);
        *(uint2*)(emit + (size_t)row * L + lane * 4) = w;
    }
}

// Kernel B: linear-domain DP, per-lane pow-2 exponent (round-4 math, proven
// absmax 0.0), now fed by an LDS ring prefetched with global_load_lds +
// counted vmcnt (compiler CANNOT sink these).
// One wave per batch; lane holds l = 4*lane..4*lane+3 (lanes 0..49 active).
__global__ __launch_bounds__(64) void dp_kernel(
    const uint16_t* __restrict__ emit, float* __restrict__ partial)
{
    __shared__ uint8_t smem[NBUF * CHB + 512];   // +512: lanes 50..63 overrun pad
    const int b    = blockIdx.x;
    const int lane = threadIdx.x;
    const uint8_t* gbase = (const uint8_t*)emit + (size_t)b * T * L * 2;

    float A0 = 0.f, A1 = 0.f, A2 = 0.f, A3 = 0.f;
    int   e  = 0;                 // per-lane log2 scale: true alpha = A * 2^e
    float f1 = 1.f, f2 = 1.f;     // carry factor 2^(e_prev - e_cur) = f1*f2
    bool first = true;

    // 6400 B chunk = 6 x (64 lanes x 16 B) + 1 x (64 lanes x 4 B)
#define STAGE(cc) do {                                                         \
    const uint8_t* _src = gbase + (size_t)(cc) * CHB;                          \
    uint8_t* _dst = &smem[((cc) & (NBUF - 1)) * CHB];                          \
    _Pragma("unroll")                                                          \
    for (int _k = 0; _k < 6; ++_k)                                             \
        __builtin_amdgcn_global_load_lds(                                      \
            (const __attribute__((address_space(1))) void*)(_src + _k * 1024 + lane * 16), \
            (__attribute__((address_space(3))) void*)(_dst + _k * 1024),       \
            16, 0, 0);                                                         \
    __builtin_amdgcn_global_load_lds(                                          \
            (const __attribute__((address_space(1))) void*)(_src + 6144 + lane * 4), \
            (__attribute__((address_space(3))) void*)(_dst + 6144),            \
            4, 0, 0);                                                          \
} while (0)

#define RESCALE() do {                                                       \
    uint32_t _b0 = __float_as_uint(A0), _b1 = __float_as_uint(A1);           \
    uint32_t _b2 = __float_as_uint(A2), _b3 = __float_as_uint(A3);           \
    uint32_t _m = max(max(_b0, _b1), max(_b2, _b3)); /* all >= 0 */          \
    uint32_t _me = _m & 0x7f800000u;                                         \
    bool _nz = (_m != 0u);                                                   \
    float _sc = _nz ? __uint_as_float(0x7F000000u - _me) : 1.0f;             \
    int _de = _nz ? (int)(_me >> 23) - 127 : 0;                              \
    int _epo = __shfl_up(e, 1);                                              \
    e = _nz ? (e + _de) : _epo;          /* zero lanes adopt upstream e */   \
    A0 *= _sc; A1 *= _sc; A2 *= _sc; A3 *= _sc;                              \
    int _ep = __shfl_up(e, 1);                                               \
    int _d = _ep - e;                                                        \
    _d = (_d < -252) ? -252 : ((_d > 252) ? 252 : _d);                       \
    int _d1 = _d >> 1, _d2 = _d - _d1;                                       \
    f1 = __uint_as_float((uint32_t)(127 + _d1) << 23);                       \
    f2 = __uint_as_float((uint32_t)(127 + _d2) << 23);                       \
} while (0)

    // prologue: stage chunks 0..6 (49 loads in flight)
    #pragma unroll
    for (int c0 = 0; c0 < 7; ++c0) STAGE(c0);

    for (int c = 0; c < NCH; ++c) {
        if (c < NCH - 7) {
            asm volatile("s_waitcnt vmcnt(42)" ::: "memory");   // chunk c landed
        } else if (c == NCH - 7) {
            asm volatile("s_waitcnt vmcnt(0)" ::: "memory");    // tail: drain all
        }
        __builtin_amdgcn_sched_barrier(0);

        const uint8_t* slot = &smem[(c & (NBUF - 1)) * CHB];

        // batch the 16 ds_read_b64 ahead of the math (2-way bank alias: free)
        uint2 vv[CH];
        #pragma unroll
        for (int j = 0; j < CH; ++j)
            vv[j] = *(const uint2*)(slot + j * 400 + lane * 8);
        __builtin_amdgcn_sched_barrier(0);

        #pragma unroll
        for (int j = 0; j < CH; ++j) {
            uint2 v = vv[j];
            float p0 = __uint_as_float(v.x << 16);
            float p1 = __uint_as_float(v.x & 0xffff0000u);
            float p2 = __uint_as_float(v.y << 16);
            float p3 = __uint_as_float(v.y & 0xffff0000u);
            float up = __shfl_up(A3, 1);
            float cm = up * f1 * f2;
            float fix = (j == 0 && first) ? 1.0f : 0.0f;
            float cin = (lane == 0) ? fix : cm;
            float n0 = p0 * (A0 + cin);
            float n1 = p1 * (A1 + A0);
            float n2 = p2 * (A2 + A1);
            float n3 = p3 * (A3 + A2);
            A0 = n0; A1 = n1; A2 = n2; A3 = n3;
            if (j == 4 || j == 9 || j == 14) RESCALE();
        }
        first = false;

        if (c + 7 < NCH) {
            // slot being overwritten (chunk c-1) fully consumed; drain reads
            asm volatile("s_waitcnt lgkmcnt(0)" ::: "memory");
            __builtin_amdgcn_sched_barrier(0);
            STAGE(c + 7);
        }
    }

#undef STAGE
#undef RESCALE

    // true log2 alpha[T-1, L-1] = log2(A3) + e, at lane 49 (l = 199)
    if (lane == 49) {
        partial[b] = (log2f(A3) + (float)e) * LN2;
    }
}

// Kernel C: loss = -mean_b log alpha_b
__global__ __launch_bounds__(64) void reduce_kernel(
    const float* __restrict__ partial, float* __restrict__ out)
{
    const int lane = threadIdx.x;
    float v = (lane < B) ? partial[lane] : 0.f;
    #pragma unroll
    for (int off = 32; off; off >>= 1) v += __shfl_xor(v, off);
    if (lane == 0) out[0] = -v * (1.0f / (float)B);
}

extern "C" void kernel_launch(void* const* d_in, const int* in_sizes, int n_in,
                              void* d_out, int out_size, void* d_ws, size_t ws_size,
                              hipStream_t stream) {
    const float* x   = (const float*)d_in[0];   // [B,T,C] fp32
    const int*   tgt = (const int*)d_in[1];     // [B,L] int32
    uint16_t* emit   = (uint16_t*)d_ws;         // [B,T,L] bf16 linear probs (51.2 MB)
    float* partial   = (float*)((char*)d_ws + (size_t)B * T * L * sizeof(uint16_t));
    float* out       = (float*)d_out;

    emit_kernel<<<B * T / 4, 256, 0, stream>>>(x, tgt, emit);
    dp_kernel<<<B, 64, 0, stream>>>(emit, partial);
    reduce_kernel<<<1, 64, 0, stream>>>(partial, out);
}